// Round 5
// baseline (88.583 us; speedup 1.0000x reference)
//
#include <hip/hip_runtime.h>

// Problem constants (fixed by the reference).
constexpr int B = 2, S = 4096, H = 16, D = 128;
constexpr int MAXSEQ = 4096;
constexpr int HD = H * D;                         // 2048 floats per row
constexpr int NBS = B * S;                        // 8192 (k/v rows)
constexpr int NCACHE = B * MAXSEQ;                // 8192 (cache rows)
constexpr long long NK = (long long)NBS * HD;     // 16,777,216 floats per tensor
constexpr long long NK4 = NK / 4;                 // in float4 units
constexpr int VR = HD / 4;                        // 512 float4 per row
constexpr int PREP_BLOCKS = 64;
static_assert(MAXSEQ == S && NBS == NCACHE, "row<->cache-row pairing requires this");

// Clang-native 16B vector (HIP float4 is a class the nontemporal builtins reject).
typedef float vf4 __attribute__((ext_vector_type(4)));

// ws layout (zeroed by one memset node each call):
//   inv[NCACHE] : i+1 of the k/v row scattered into cache row c, or 0 (keep old)
//   cnt[8]      : 0=hits 1=num_updates 2=any_update 3=max(max_pos+1,0) 4=is_u8

// Parallel prep: dtype-detect, build inverse scatter map, scalar stats.
// Positions are distinct per batch row, so inv writes are conflict-free.
__global__ __launch_bounds__(256) void prep_kernel(
    const int* __restrict__ pos, const void* __restrict__ um_raw,
    const int* __restrict__ cvl_p, int* __restrict__ inv, int* __restrict__ cnt)
{
    const int tid = threadIdx.x;

    // Per-block dtype detection on the first 512 bytes of the mask buffer.
    // int32 0/1 data never exceeds 1; byte-bool data's int32 view exceeds 1
    // with P=7/8 per word -> P(misdetect over 128 words) = (1/8)^128 ~ 0.
    __shared__ int s_u8;
    if (tid == 0) s_u8 = 0;
    __syncthreads();
    if (tid < 128 && (unsigned)((const int*)um_raw)[tid] > 1u) atomicOr(&s_u8, 1);
    __syncthreads();
    const int is_u8 = s_u8;
    if (blockIdx.x == 0 && tid == 0) cnt[4] = is_u8;   // for main_kernel

    const int cvl = cvl_p[0];
    const unsigned char* m8 = (const unsigned char*)um_raw;
    const int* m32 = (const int*)um_raw;

    int hits = 0, upd = 0, anyu = 0, maxp1 = 0;        // maxp1 = max(pos+1, 0)
    for (int i = blockIdx.x * 256 + tid; i < NBS; i += 256 * PREP_BLOCKS) {
        const int p = pos[i];
        const int um = is_u8 ? (m8[i] != 0) : (m32[i] != 0);
        const int b = i >> 12;                         // i / S, S = 4096
        hits += (p < cvl) ? 1 : 0;
        upd += um;
        anyu |= um;
        const int p1 = p + 1;
        maxp1 = p1 > maxp1 ? p1 : maxp1;
        if (um && (unsigned)p < (unsigned)MAXSEQ)
            inv[b * MAXSEQ + p] = i + 1;
    }
    for (int off = 32; off; off >>= 1) {
        hits += __shfl_down(hits, off);
        upd  += __shfl_down(upd, off);
        anyu |= __shfl_down(anyu, off);
        const int o = __shfl_down(maxp1, off);
        maxp1 = o > maxp1 ? o : maxp1;
    }
    if ((tid & 63) == 0) {
        atomicAdd(&cnt[0], hits);
        atomicAdd(&cnt[1], upd);
        atomicOr(&cnt[2], anyu);
        atomicMax(&cnt[3], maxp1);
    }
}

// Main kernel: block t owns k/v row t AND cache row t (same flat index since
// MAXSEQ==S). Each input row is read from HBM exactly once. Concurrent
// per-block streams live exactly 64MB apart (output tensors) — rotate each
// load+store unit to a different wave-aligned intra-row offset so their
// address bits 10-12 differ (anti channel/bank aliasing). Shifts are
// multiples of 64 vf4 (1KB) so every wave still issues contiguous 1KB bursts.
__global__ __launch_bounds__(256) void main_kernel(
    const vf4* __restrict__ k, const vf4* __restrict__ v,
    const vf4* __restrict__ ck, const vf4* __restrict__ cv,
    const int* __restrict__ pos, const void* __restrict__ um_raw,
    const int* __restrict__ cvl_p, const int* __restrict__ inv,
    const int* __restrict__ cnt, vf4* __restrict__ out,
    float* __restrict__ scalars)
{
    const int t = blockIdx.x;
    const int tid = threadIdx.x;

    if (t == 0 && tid == 0) {   // finalize scalar outputs (cnt complete: prep done)
        const int h = cnt[0], u = cnt[1], au = cnt[2], mp1 = cnt[3];
        const float ema_h = 0.01f * (float)h;
        const float ema_m = 0.01f * ((float)NBS - (float)h);
        scalars[0] = ema_h / (ema_h + ema_m + 1e-8f);
        const int cvl0 = cvl_p[0];
        int hi = cvl0 > mp1 ? cvl0 : mp1;              // max(cvl, max_pos+1)
        if (hi > MAXSEQ) hi = MAXSEQ;
        scalars[1] = (float)(au ? hi : cvl0);
        scalars[2] = (float)u;
    }

    const int p = pos[t];
    const int is_u8 = cnt[4];
    const int um = is_u8 ? (((const unsigned char*)um_raw)[t] != 0)
                         : (((const int*)um_raw)[t] != 0);
    const int cvl = cvl_p[0];
    const int b = t >> 12;
    const bool gather = (p < cvl) && !um;
    const bool scat = um && ((unsigned)p < (unsigned)MAXSEQ);
    const int pc = ((unsigned)p < (unsigned)MAXSEQ) ? p : 0;       // safe index
    const long long row  = (long long)t * VR;
    const long long crow = (long long)(b * MAXSEQ + pc) * VR;      // gather src / scatter dst
    const bool copyc = inv[t] == 0;                    // own cache row not scattered-into
    const bool reuse = gather && (crow == row);        // gather source == own cache row

    const vf4* sK = gather ? (ck + crow) : (k + row);
    const vf4* sV = gather ? (cv + crow) : (v + row);
    vf4* dK = out + row;                               // k_out
    vf4* dV = out + NK4 + row;                         // v_out
    vf4* xK = out + 2 * NK4 + crow;                    // scatter dest (if scat)
    vf4* xV = out + 3 * NK4 + crow;
    const vf4* csK = ck + row;                         // own cache row src
    const vf4* csV = cv + row;
    vf4* cdK = out + 2 * NK4 + row;                    // own cache row dest
    vf4* cdV = out + 3 * NK4 + row;

    #pragma unroll
    for (int ii = 0; ii < 2; ++ii) {
        const int i  = tid + ii * 256;                 // K-unit index
        const int iv = (i + 128) & 511;                // V-unit: +2KB
        const vf4 a = sK[i];
        const vf4 w = sV[iv];
        __builtin_nontemporal_store(a, &dK[i]);
        __builtin_nontemporal_store(w, &dV[iv]);
        if (scat) {
            __builtin_nontemporal_store(a, &xK[i]);
            __builtin_nontemporal_store(w, &xV[iv]);
        }
        if (copyc) {
            if (reuse) {
                __builtin_nontemporal_store(a, &cdK[i]);
                __builtin_nontemporal_store(w, &cdV[iv]);
            } else {
                const int ic  = (i + 64) & 511;        // CK-unit: +1KB
                const int icv = (i + 192) & 511;       // CV-unit: +3KB
                __builtin_nontemporal_store(csK[ic],  &cdK[ic]);
                __builtin_nontemporal_store(csV[icv], &cdV[icv]);
            }
        }
    }
}

extern "C" void kernel_launch(void* const* d_in, const int* in_sizes, int n_in,
                              void* d_out, int out_size, void* d_ws, size_t ws_size,
                              hipStream_t stream) {
    const float* k  = (const float*)d_in[0];
    const float* v  = (const float*)d_in[1];
    const float* ck = (const float*)d_in[2];
    const float* cv = (const float*)d_in[3];
    const int* pos  = (const int*)d_in[4];
    const void* um  = d_in[5];
    const int* cvl  = (const int*)d_in[6];
    float* out = (float*)d_out;

    int* inv = (int*)d_ws;          // NCACHE ints
    int* cnt = inv + NCACHE;        // 8 ints

    hipMemsetAsync(d_ws, 0, (size_t)(NCACHE + 8) * sizeof(int), stream);
    prep_kernel<<<PREP_BLOCKS, 256, 0, stream>>>(pos, um, cvl, inv, cnt);
    main_kernel<<<NBS, 256, 0, stream>>>(
        (const vf4*)k, (const vf4*)v, (const vf4*)ck, (const vf4*)cv,
        pos, um, cvl, inv, cnt, (vf4*)out, out + 4 * NK);
}